// Round 5
// baseline (599.353 us; speedup 1.0000x reference)
//
#include <hip/hip_runtime.h>
#include <math.h>

typedef __attribute__((ext_vector_type(8))) _Float16 f16x8;
typedef __attribute__((ext_vector_type(4))) _Float16 f16x4;
typedef __attribute__((ext_vector_type(4))) float f32x4;
typedef __attribute__((ext_vector_type(4))) short s16x4;

#define MFMA16(a, b, c) __builtin_amdgcn_mfma_f32_16x16x32_f16(a, b, c, 0, 0, 0)

// ---------------------------------------------------------------------------
// Precision: GEMMs split-fp16 (a = ah + al/2048) ~2^-22 rel. msc int16 with
// per-(row,48-block) fp32 scale (~1.5e-5). h stored fp16-hi + e5m2-lo
// (x2048) planes = 3 B/feature, ~6e-5 rel per quantization event.
// r15 measured absmax 0.0039 (h term invisible vs msc baseline); predicted
// here <=0.008 vs threshold 1.9e-2.
//
// Round 16: decode-cost fix for r15's h planes. r15's fp8-e4m3 lo plane
// made tail/conv VALU-bound (tail 78 us, VALUBusy 63%: ~10 VALU ops per
// element via __hip_fp8 cast). e5m2 = top byte of the f16 bit pattern:
// decode is (byte<<8) reinterpreted as f16 (~6 ops per 8 elements, exact
// for all e5m2 values), encode is (bits+0x80)>>8 (correct RN rounding).
// Same byte counts as r15; aggregate structure (r14: wave-per-node,
// 4-chain ILP, own grid) frozen at its compulsory-fetch floor
// (gather 131 MB = 20 MB msc table x 8 XCDs x 0.86 coverage).
// ---------------------------------------------------------------------------

__device__ __forceinline__ unsigned char enc_e5m2(float x) {
    unsigned short b = __builtin_bit_cast(unsigned short, (_Float16)x);
    b = (unsigned short)(b + 0x80);  // round mantissa to 2 bits
    return (unsigned char)(b >> 8);
}
__device__ __forceinline__ f16x8 dec8(uint2 w) {
    unsigned int r0 = ((w.x & 0x000000FFu) << 8) | ((w.x & 0x0000FF00u) << 16);
    unsigned int r1 = ((w.x >> 8) & 0x0000FF00u) | (w.x & 0xFF000000u);
    unsigned int r2 = ((w.y & 0x000000FFu) << 8) | ((w.y & 0x0000FF00u) << 16);
    unsigned int r3 = ((w.y >> 8) & 0x0000FF00u) | (w.y & 0xFF000000u);
    uint4 u = {r0, r1, r2, r3};
    return __builtin_bit_cast(f16x8, u);
}
__device__ __forceinline__ f16x4 dec4(unsigned int w) {
    unsigned int r0 = ((w & 0x000000FFu) << 8) | ((w & 0x0000FF00u) << 16);
    unsigned int r1 = ((w >> 8) & 0x0000FF00u) | (w & 0xFF000000u);
    uint2 u = {r0, r1};
    return __builtin_bit_cast(f16x4, u);
}

// ------------------------- graph setup -------------------------------------
__global__ void scan1_kernel(const int* __restrict__ cnt, int M,
                             int* __restrict__ rowptr, int* __restrict__ bsum,
                             float* __restrict__ dinv) {
    __shared__ int s[256];
    int t = threadIdx.x;
    int i = blockIdx.x * 256 + t;
    int v = (i < M) ? cnt[i] : 0;
    s[t] = v; __syncthreads();
    for (int o = 1; o < 256; o <<= 1) {
        int x = (t >= o) ? s[t - o] : 0;
        __syncthreads();
        s[t] += x;
        __syncthreads();
    }
    if (i < M) {
        rowptr[i] = s[t] - v;
        dinv[i] = rsqrtf((float)v + 1.0f);  // deg = in-deg + self-loop
    }
    if (t == 255) bsum[blockIdx.x] = s[255];
}

__global__ void scan2_kernel(const int* __restrict__ bsum, int nb, int* __restrict__ boff) {
    __shared__ int s[256];
    int t = threadIdx.x;
    int v = (t < nb) ? bsum[t] : 0;
    s[t] = v; __syncthreads();
    for (int o = 1; o < 256; o <<= 1) {
        int x = (t >= o) ? s[t - o] : 0;
        __syncthreads();
        s[t] += x;
        __syncthreads();
    }
    if (t < nb) boff[t] = s[t] - v;
}

__global__ void scan3_kernel(int* __restrict__ rowptr, int M, int E, const int* __restrict__ boff) {
    int i = blockIdx.x * 256 + threadIdx.x;
    if (i < M) rowptr[i] += boff[blockIdx.x];
    if (i == M) rowptr[M] = E;
}

__global__ void fill_kernel(const int* __restrict__ src, const int* __restrict__ dst, int E,
                            const int* __restrict__ rowptr, int* __restrict__ cursor,
                            int* __restrict__ csr) {
    int i = blockIdx.x * blockDim.x + threadIdx.x;
    if (i < E) {
        int d = dst[i];
        int slot = atomicAdd(&cursor[d], 1);
        csr[rowptr[d] + slot] = src[i];
    }
}

// ---------------- fused prep: count + pack_b --------------------------------
struct WSeg { const float* src; _Float16* dh; _Float16* dl; int K; int N; };
struct WSegs { WSeg s[8]; };

__global__ void prep_kernel(const int* __restrict__ dst, int E, int* __restrict__ cnt,
                            WSegs segs, int nCount) {
    int b = blockIdx.x;
    if (b < nCount) {
        int i = b * 256 + threadIdx.x;
        if (i < E) atomicAdd(&cnt[dst[i]], 1);
        return;
    }
    b -= nCount;
    // pack_b: frag-major WT planes, flat i = ((s*G+g)*64+l)*8+j
    WSeg sg = segs.s[b / 144];
    int i = (b % 144) * 256 + threadIdx.x;
    if (i >= sg.K * sg.N) return;
    int G = sg.N >> 4;
    int s = i / (G * 512);
    int r = i - s * (G * 512);
    int g = r >> 9;
    int r2 = r & 511;
    int l = r2 >> 3, j = r2 & 7;
    int n = g * 16 + (l & 15);
    int k = s * 32 + (l >> 4) * 8 + j;
    float w = sg.src[(size_t)k * sg.N + n];
    _Float16 hi = (_Float16)w;
    sg.dh[i] = hi;
    sg.dl[i] = (_Float16)((w - (float)hi) * 2048.f);
}

// ---------------------------------------------------------------------------
// Shared GEMM epilogue (NN=192, 4 waves x 48 cols, C/D col=lane&15,
// row=quad*4+reg). OM bit0: int16+scale msc out. OM bit1: global h planes
// (fp16 hi + e5m2 lo). OM bit2: LDS pair-format stage (page-local).
// h plane layout: [page][slab s=col>>5][row 0..31][32], elem (kk=col&31):
// chunk c=kk>>3 stored at slot ph=c^(row&3), j=kk&7.
// ---------------------------------------------------------------------------
template <int ACT, int OM>
__device__ __forceinline__ void epi192(
    f32x4 (&acc)[2][3], f32x4 (&acc2)[2][3],
    const float* __restrict__ bias, const float* __restrict__ rowscale,
    short* __restrict__ Cq, float* __restrict__ Cs,
    _Float16* __restrict__ ChH, unsigned char* __restrict__ ChL,
    _Float16* CpL,
    int row0, int M) {
    const int tid = threadIdx.x;
    const int wave = tid >> 6, lane = tid & 63;
    const int quad = lane >> 4, l16 = lane & 15;
    const int n0 = wave * 48;
    float bv[3];
#pragma unroll
    for (int nt = 0; nt < 3; ++nt) bv[nt] = bias ? bias[n0 + nt * 16 + l16] : 0.f;
#pragma unroll
    for (int mt = 0; mt < 2; ++mt)
#pragma unroll
        for (int i = 0; i < 4; ++i) {
            int rl = mt * 16 + quad * 4 + i;
            int row = row0 + rl;
            bool ok = row < M;
            float v[3] = {0.f, 0.f, 0.f};
            if (ok) {
                float rs = rowscale ? rowscale[row] : 1.f;
#pragma unroll
                for (int nt = 0; nt < 3; ++nt) {
                    float t = acc[mt][nt][i] + acc2[mt][nt][i] * (1.f / 2048.f) + bv[nt];
                    if (ACT == 1) t = fmaxf(t, 0.f);
                    v[nt] = t * rs;
                }
            }
            if (OM & 1) {
                if (ok) {
                    // row-block max: the 16 lanes of this quad hold this
                    // row's 48 cols (3 regs each) -> butterfly, no LDS.
                    float m = fmaxf(fmaxf(fabsf(v[0]), fabsf(v[1])), fabsf(v[2]));
#pragma unroll
                    for (int d = 1; d < 16; d <<= 1) m = fmaxf(m, __shfl_xor(m, d));
                    float inv = (m > 0.f) ? 32767.f / m : 0.f;
#pragma unroll
                    for (int nt = 0; nt < 3; ++nt) {
                        int col = n0 + nt * 16 + l16;
                        Cq[(size_t)row * 192 + col] = (short)rintf(v[nt] * inv);
                    }
                    if (l16 == 0) Cs[row * 4 + wave] = m * (1.f / 32767.f);
                }
            }
            if (OM & 6) {
#pragma unroll
                for (int nt = 0; nt < 3; ++nt) {
                    int col = n0 + nt * 16 + l16;
                    _Float16 hi = (_Float16)v[nt];
                    float lof = (v[nt] - (float)hi) * 2048.f;
                    if (OM & 2) {
                        if (ok) {
                            int s = col >> 5, kk = col & 31;
                            int ph = (kk >> 3) ^ (rl & 3), j = kk & 7;
                            size_t base = ((size_t)((row >> 5) * 6 + s) * 32 + (row & 31)) * 32 + ph * 8 + j;
                            ChH[base] = hi;
                            ChL[base] = enc_e5m2(lof);
                        }
                    }
                    if (OM & 4) {
                        int os = col >> 5, ocn = (col >> 3) & 3, j = col & 7;
                        int ph2 = ocn ^ (rl & 7);
                        int baseL = (os * 32 + rl) * 64;
                        CpL[baseL + ph2 * 8 + j] = hi;
                        CpL[baseL + (ph2 ^ 4) * 8 + j] = (_Float16)lof;
                    }
                }
            }
        }
}

// GEMM K=192. AF=0: A is a pair-format page (LDS stage, 64 f16/row-slab).
// AF=1: A is global hi/lo planes (fp16 + e5m2, 32/row-slab each).
template <int ACT, int OM, int AF>
__device__ __forceinline__ void gemm192(
    const _Float16* Ah_, const unsigned char* Al_,
    const _Float16* __restrict__ Bph, const _Float16* __restrict__ Bpl,
    const float* __restrict__ bias, const float* __restrict__ rowscale,
    short* __restrict__ Cq, float* __restrict__ Cs,
    _Float16* __restrict__ ChH, unsigned char* __restrict__ ChL,
    _Float16* CpL,
    int row0, int M) {
    const int tid = threadIdx.x;
    const int wave = tid >> 6, lane = tid & 63;
    const int quad = lane >> 4, l16 = lane & 15;
    const int g0 = (wave * 48) >> 4;
    f32x4 acc[2][3], acc2[2][3];
#pragma unroll
    for (int mt = 0; mt < 2; ++mt)
#pragma unroll
        for (int nt = 0; nt < 3; ++nt) {
            acc[mt][nt] = (f32x4){0.f, 0.f, 0.f, 0.f};
            acc2[mt][nt] = (f32x4){0.f, 0.f, 0.f, 0.f};
        }
#pragma unroll
    for (int s = 0; s < 6; ++s) {
        f16x8 ah[2], al[2];
#pragma unroll
        for (int mt = 0; mt < 2; ++mt) {
            int R = mt * 16 + l16;
            if (AF == 0) {
                int ph = quad ^ (R & 7);
                ah[mt] = *reinterpret_cast<const f16x8*>(Ah_ + s * 2048 + R * 64 + ph * 8);
                al[mt] = *reinterpret_cast<const f16x8*>(Ah_ + s * 2048 + R * 64 + (ph ^ 4) * 8);
            } else {
                int ph = quad ^ (R & 3);
                size_t o = (size_t)s * 1024 + R * 32 + ph * 8;
                ah[mt] = *reinterpret_cast<const f16x8*>(Ah_ + o);
                al[mt] = dec8(*reinterpret_cast<const uint2*>(Al_ + o));
            }
        }
        f16x8 bh[3], bl[3];
#pragma unroll
        for (int nt = 0; nt < 3; ++nt) {
            size_t o = ((size_t)(s * 12 + g0 + nt) * 64 + lane) * 8;
            bh[nt] = *reinterpret_cast<const f16x8*>(Bph + o);
            bl[nt] = *reinterpret_cast<const f16x8*>(Bpl + o);
        }
#pragma unroll
        for (int mt = 0; mt < 2; ++mt)
#pragma unroll
            for (int nt = 0; nt < 3; ++nt) {
                acc[mt][nt] = MFMA16(ah[mt], bh[nt], acc[mt][nt]);
                acc2[mt][nt] = MFMA16(ah[mt], bl[nt], acc2[mt][nt]);
                acc2[mt][nt] = MFMA16(al[mt], bh[nt], acc2[mt][nt]);
            }
    }
    epi192<ACT, OM>(acc, acc2, bias, rowscale, Cq, Cs, ChH, ChL, CpL, row0, M);
}

// ---------------------------------------------------------------------------
// HEAD: h1 = x@Wp + bp (x direct f32 loads) -> global h planes + LDS pair
// stage; msc0 = (h1@W0)*dinv -> int16+scale.
// ---------------------------------------------------------------------------
__global__ __launch_bounds__(256, 4) void head_kernel(
    const float* __restrict__ x,
    const _Float16* __restrict__ WpPh, const _Float16* __restrict__ WpPl,
    const float* __restrict__ bp,
    const _Float16* __restrict__ W0h, const _Float16* __restrict__ W0l,
    const float* __restrict__ dinv,
    _Float16* __restrict__ hH, unsigned char* __restrict__ hL,
    short* __restrict__ mscq, float* __restrict__ mscs,
    int M) {
    __shared__ __align__(16) _Float16 stage[6 * 2048];
    const int tid = threadIdx.x;
    const int wave = tid >> 6, lane = tid & 63;
    const int quad = lane >> 4, l16 = lane & 15;
    const int g0 = (wave * 48) >> 4;
    const int row0 = blockIdx.x * 32;

    f32x4 acc[2][3], acc2[2][3];
#pragma unroll
    for (int mt = 0; mt < 2; ++mt)
#pragma unroll
        for (int nt = 0; nt < 3; ++nt) {
            acc[mt][nt] = (f32x4){0.f, 0.f, 0.f, 0.f};
            acc2[mt][nt] = (f32x4){0.f, 0.f, 0.f, 0.f};
        }
#pragma unroll
    for (int s = 0; s < 4; ++s) {  // KK=128 -> 4 slabs
        f16x8 ah[2], al[2];
#pragma unroll
        for (int mt = 0; mt < 2; ++mt) {
            int R = mt * 16 + l16, row = row0 + R;
            f32x4 xa = (f32x4){0.f, 0.f, 0.f, 0.f}, xb = xa;
            if (row < M) {
                const float* xr = x + (size_t)row * 128 + s * 32 + quad * 8;
                xa = *reinterpret_cast<const f32x4*>(xr);
                xb = *reinterpret_cast<const f32x4*>(xr + 4);
            }
#pragma unroll
            for (int j = 0; j < 4; ++j) {
                _Float16 ha = (_Float16)xa[j], hb = (_Float16)xb[j];
                ah[mt][j] = ha; ah[mt][j + 4] = hb;
                al[mt][j] = (_Float16)((xa[j] - (float)ha) * 2048.f);
                al[mt][j + 4] = (_Float16)((xb[j] - (float)hb) * 2048.f);
            }
        }
        f16x8 bh[3], bl[3];
#pragma unroll
        for (int nt = 0; nt < 3; ++nt) {
            size_t o = ((size_t)(s * 12 + g0 + nt) * 64 + lane) * 8;
            bh[nt] = *reinterpret_cast<const f16x8*>(WpPh + o);
            bl[nt] = *reinterpret_cast<const f16x8*>(WpPl + o);
        }
#pragma unroll
        for (int mt = 0; mt < 2; ++mt)
#pragma unroll
            for (int nt = 0; nt < 3; ++nt) {
                acc[mt][nt] = MFMA16(ah[mt], bh[nt], acc[mt][nt]);
                acc2[mt][nt] = MFMA16(ah[mt], bl[nt], acc2[mt][nt]);
                acc2[mt][nt] = MFMA16(al[mt], bh[nt], acc2[mt][nt]);
            }
    }
    epi192<0, 6>(acc, acc2, bp, nullptr, nullptr, nullptr, hH, hL, stage, row0, M);
    __syncthreads();
    gemm192<0, 1, 0>(stage, nullptr, W0h, W0l, nullptr, dinv,
                     mscq, mscs, nullptr, nullptr, nullptr, row0, M);
}

// ---------------------------------------------------------------------------
// conv GEMM: msc = (h@W)*dinv -> int16+scale. A read from global h planes.
// ---------------------------------------------------------------------------
__global__ __launch_bounds__(256, 4) void conv_gemm_kernel(
    const _Float16* __restrict__ hH, const unsigned char* __restrict__ hL,
    const _Float16* __restrict__ Bh, const _Float16* __restrict__ Bl,
    const float* __restrict__ dinv,
    short* __restrict__ mq, float* __restrict__ ms, int M) {
    gemm192<0, 1, 1>(hH + (size_t)blockIdx.x * 6144, hL + (size_t)blockIdx.x * 6144,
                     Bh, Bl, nullptr, dinv, mq, ms, nullptr, nullptr, nullptr,
                     blockIdx.x * 32, M);
}

// ---------------------------------------------------------------------------
// int16 whole-row aggregation (r14 structure: wave-per-node, 4-chain ILP).
// h RMW on fp16+e5m2 planes. h = h + relu(dinv[n]*sum + B).
// ---------------------------------------------------------------------------
__global__ __launch_bounds__(256) void aggregate_kernel(
    const short* __restrict__ mscq, const float* __restrict__ mscs,
    const int* __restrict__ csr, const int* __restrict__ rowptr,
    const float* __restrict__ dinv, const float* __restrict__ bias,
    _Float16* __restrict__ hH, unsigned char* __restrict__ hL, int M) {
    int wid = (blockIdx.x * 256 + threadIdx.x) >> 6;
    int lane = threadIdx.x & 63;
    if (wid >= M || lane >= 48) return;
    const int soff = lane / 12;
    const int f0 = lane * 4;

    // self-loop term
    s16x4 q0 = *reinterpret_cast<const s16x4*>(mscq + (size_t)wid * 192 + f0);
    float f0v = mscs[wid * 4 + soff];
    float4 a0, a1, a2, a3;
    a0.x = (float)q0[0] * f0v; a0.y = (float)q0[1] * f0v;
    a0.z = (float)q0[2] * f0v; a0.w = (float)q0[3] * f0v;
    a1 = make_float4(0.f, 0.f, 0.f, 0.f);
    a2 = a1; a3 = a1;

    int beg = rowptr[wid], end = rowptr[wid + 1];
    int e = beg;
    for (; e + 3 < end; e += 4) {
        int sa = csr[e], sb = csr[e + 1], sc = csr[e + 2], sd = csr[e + 3];
        s16x4 qa = *reinterpret_cast<const s16x4*>(mscq + (size_t)sa * 192 + f0);
        float fa = mscs[sa * 4 + soff];
        s16x4 qb = *reinterpret_cast<const s16x4*>(mscq + (size_t)sb * 192 + f0);
        float fb = mscs[sb * 4 + soff];
        s16x4 qc = *reinterpret_cast<const s16x4*>(mscq + (size_t)sc * 192 + f0);
        float fc = mscs[sc * 4 + soff];
        s16x4 qd = *reinterpret_cast<const s16x4*>(mscq + (size_t)sd * 192 + f0);
        float fd = mscs[sd * 4 + soff];
        a0.x = fmaf((float)qa[0], fa, a0.x);
        a0.y = fmaf((float)qa[1], fa, a0.y);
        a0.z = fmaf((float)qa[2], fa, a0.z);
        a0.w = fmaf((float)qa[3], fa, a0.w);
        a1.x = fmaf((float)qb[0], fb, a1.x);
        a1.y = fmaf((float)qb[1], fb, a1.y);
        a1.z = fmaf((float)qb[2], fb, a1.z);
        a1.w = fmaf((float)qb[3], fb, a1.w);
        a2.x = fmaf((float)qc[0], fc, a2.x);
        a2.y = fmaf((float)qc[1], fc, a2.y);
        a2.z = fmaf((float)qc[2], fc, a2.z);
        a2.w = fmaf((float)qc[3], fc, a2.w);
        a3.x = fmaf((float)qd[0], fd, a3.x);
        a3.y = fmaf((float)qd[1], fd, a3.y);
        a3.z = fmaf((float)qd[2], fd, a3.z);
        a3.w = fmaf((float)qd[3], fd, a3.w);
    }
    for (; e + 1 < end; e += 2) {
        int sa = csr[e], sb = csr[e + 1];
        s16x4 qa = *reinterpret_cast<const s16x4*>(mscq + (size_t)sa * 192 + f0);
        float fa = mscs[sa * 4 + soff];
        s16x4 qb = *reinterpret_cast<const s16x4*>(mscq + (size_t)sb * 192 + f0);
        float fb = mscs[sb * 4 + soff];
        a0.x = fmaf((float)qa[0], fa, a0.x);
        a0.y = fmaf((float)qa[1], fa, a0.y);
        a0.z = fmaf((float)qa[2], fa, a0.z);
        a0.w = fmaf((float)qa[3], fa, a0.w);
        a1.x = fmaf((float)qb[0], fb, a1.x);
        a1.y = fmaf((float)qb[1], fb, a1.y);
        a1.z = fmaf((float)qb[2], fb, a1.z);
        a1.w = fmaf((float)qb[3], fb, a1.w);
    }
    if (e < end) {
        int sa = csr[e];
        s16x4 qa = *reinterpret_cast<const s16x4*>(mscq + (size_t)sa * 192 + f0);
        float fa = mscs[sa * 4 + soff];
        a0.x = fmaf((float)qa[0], fa, a0.x);
        a0.y = fmaf((float)qa[1], fa, a0.y);
        a0.z = fmaf((float)qa[2], fa, a0.z);
        a0.w = fmaf((float)qa[3], fa, a0.w);
    }
    float4 a;
    a.x = (a0.x + a1.x) + (a2.x + a3.x);
    a.y = (a0.y + a1.y) + (a2.y + a3.y);
    a.z = (a0.z + a1.z) + (a2.z + a3.z);
    a.w = (a0.w + a1.w) + (a2.w + a3.w);

    float dn = dinv[wid];
    float4 b = reinterpret_cast<const float4*>(bias)[lane];

    // h plane granule for features f0 = lane*4 .. +4
    int s = f0 >> 5, kk = f0 & 31;
    int r = wid & 31;
    int ph = (kk >> 3) ^ (r & 3), j = f0 & 7;
    size_t hb = ((size_t)((wid >> 5) * 6 + s) * 32 + r) * 32 + ph * 8 + j;
    f16x4* hp = reinterpret_cast<f16x4*>(hH + hb);
    unsigned int* lp = reinterpret_cast<unsigned int*>(hL + hb);
    f16x4 hh = *hp;
    f16x4 hl = dec4(*lp);
    float4 hv;
    hv.x = (float)hh[0] + (float)hl[0] * (1.f / 2048.f) + fmaxf(a.x * dn + b.x, 0.f);
    hv.y = (float)hh[1] + (float)hl[1] * (1.f / 2048.f) + fmaxf(a.y * dn + b.y, 0.f);
    hv.z = (float)hh[2] + (float)hl[2] * (1.f / 2048.f) + fmaxf(a.z * dn + b.z, 0.f);
    hv.w = (float)hh[3] + (float)hl[3] * (1.f / 2048.f) + fmaxf(a.w * dn + b.w, 0.f);
    f16x4 nh = {(_Float16)hv.x, (_Float16)hv.y, (_Float16)hv.z, (_Float16)hv.w};
    unsigned char b0 = enc_e5m2((hv.x - (float)nh[0]) * 2048.f);
    unsigned char b1 = enc_e5m2((hv.y - (float)nh[1]) * 2048.f);
    unsigned char b2 = enc_e5m2((hv.z - (float)nh[2]) * 2048.f);
    unsigned char b3 = enc_e5m2((hv.w - (float)nh[3]) * 2048.f);
    *hp = nh;
    *lp = (unsigned int)b0 | ((unsigned int)b1 << 8) |
          ((unsigned int)b2 << 16) | ((unsigned int)b3 << 24);
}

// ---------------------------------------------------------------------------
// TAIL (no gather): single s-loop computes p1 = relu(h@Wp1+bp1) AND
// r = relu(h@Wr1+br1) -- the r-GEMM's A fragments are p1's ah[wave>>1],
// so h is read ONCE. p1 -> LDS pair stage; p2 = relu(p1@Wp2+b); finalize.
// ---------------------------------------------------------------------------
__global__ __launch_bounds__(256, 4) void tail_kernel(
    const _Float16* __restrict__ hH, const unsigned char* __restrict__ hL,
    const _Float16* __restrict__ W1h, const _Float16* __restrict__ W1l,
    const float* __restrict__ bp1,
    const _Float16* __restrict__ W2h, const _Float16* __restrict__ W2l,
    const _Float16* __restrict__ Wrh, const _Float16* __restrict__ Wrl,
    const float* __restrict__ bp2, const float* __restrict__ br1,
    const float* __restrict__ Wp3, const float* __restrict__ bp3,
    const float* __restrict__ Wr2, const float* __restrict__ br2,
    float* __restrict__ out, int M) {
    __shared__ __align__(16) _Float16 stage_p[6 * 2048];
    float* p2t = reinterpret_cast<float*>(stage_p);          // alias after reads
    float* rbt = reinterpret_cast<float*>(stage_p) + 32 * 96;
    const int tid = threadIdx.x;
    const int wave = tid >> 6, lane = tid & 63;
    const int quad = lane >> 4, l16 = lane & 15;
    const int g0 = (wave * 48) >> 4;     // p1 cols (N=192)
    const int m0 = (wave >> 1) * 16;     // p2/r m-half
    const int n0t = (wave & 1) * 48;     // p2/r n-half (N=96)
    const int g0t = n0t >> 4;
    const int wh = wave >> 1;
    const int row0 = blockIdx.x * 32;
    const _Float16* hpH = hH + (size_t)blockIdx.x * 6144;
    const unsigned char* hpL = hL + (size_t)blockIdx.x * 6144;

    f32x4 aB[2][3], aB2[2][3], aR[3], aR2[3];
#pragma unroll
    for (int nt = 0; nt < 3; ++nt) {
        aR[nt] = (f32x4){0.f, 0.f, 0.f, 0.f};
        aR2[nt] = aR[nt];
#pragma unroll
        for (int mt = 0; mt < 2; ++mt) { aB[mt][nt] = aR[nt]; aB2[mt][nt] = aR[nt]; }
    }

#pragma unroll
    for (int s = 0; s < 6; ++s) {
        f16x8 ah[2], al[2];
#pragma unroll
        for (int mt = 0; mt < 2; ++mt) {
            int R = mt * 16 + l16;
            int ph = quad ^ (R & 3);
            size_t o = (size_t)s * 1024 + R * 32 + ph * 8;
            ah[mt] = *reinterpret_cast<const f16x8*>(hpH + o);
            al[mt] = dec8(*reinterpret_cast<const uint2*>(hpL + o));
        }
        {   // p1 GEMM (N=192)
            f16x8 b1h[3], b1l[3];
#pragma unroll
            for (int nt = 0; nt < 3; ++nt) {
                size_t o = ((size_t)(s * 12 + g0 + nt) * 64 + lane) * 8;
                b1h[nt] = *reinterpret_cast<const f16x8*>(W1h + o);
                b1l[nt] = *reinterpret_cast<const f16x8*>(W1l + o);
            }
#pragma unroll
            for (int mt = 0; mt < 2; ++mt)
#pragma unroll
                for (int nt = 0; nt < 3; ++nt) {
                    aB[mt][nt] = MFMA16(ah[mt], b1h[nt], aB[mt][nt]);
                    aB2[mt][nt] = MFMA16(ah[mt], b1l[nt], aB2[mt][nt]);
                    aB2[mt][nt] = MFMA16(al[mt], b1h[nt], aB2[mt][nt]);
                }
        }
        {   // r GEMM (N=96) reusing ah[wh]/al[wh]
            f16x8 brh[3], brl[3];
#pragma unroll
            for (int nt = 0; nt < 3; ++nt) {
                size_t o = ((size_t)(s * 6 + g0t + nt) * 64 + lane) * 8;
                brh[nt] = *reinterpret_cast<const f16x8*>(Wrh + o);
                brl[nt] = *reinterpret_cast<const f16x8*>(Wrl + o);
            }
#pragma unroll
            for (int nt = 0; nt < 3; ++nt) {
                aR[nt] = MFMA16(ah[wh], brh[nt], aR[nt]);
                aR2[nt] = MFMA16(ah[wh], brl[nt], aR2[nt]);
                aR2[nt] = MFMA16(al[wh], brh[nt], aR2[nt]);
            }
        }
    }
    epi192<1, 4>(aB, aB2, bp1, nullptr, nullptr, nullptr, nullptr, nullptr,
                 stage_p, row0, M);
    __syncthreads();

    // p2 GEMM (N=96) from stage_p
    f32x4 aP[3], aP2[3];
#pragma unroll
    for (int nt = 0; nt < 3; ++nt) {
        aP[nt] = (f32x4){0.f, 0.f, 0.f, 0.f};
        aP2[nt] = aP[nt];
    }
#pragma unroll
    for (int s = 0; s < 6; ++s) {
        const int R = m0 + l16;
        const int ph = quad ^ (R & 7);
        f16x8 p1h = *reinterpret_cast<const f16x8*>(stage_p + s * 2048 + R * 64 + ph * 8);
        f16x8 p1l = *reinterpret_cast<const f16x8*>(stage_p + s * 2048 + R * 64 + (ph ^ 4) * 8);
        f16x8 b2h[3], b2l[3];
#pragma unroll
        for (int nt = 0; nt < 3; ++nt) {
            size_t o = ((size_t)(s * 6 + g0t + nt) * 64 + lane) * 8;
            b2h[nt] = *reinterpret_cast<const f16x8*>(W2h + o);
            b2l[nt] = *reinterpret_cast<const f16x8*>(W2l + o);
        }
#pragma unroll
        for (int nt = 0; nt < 3; ++nt) {
            aP[nt] = MFMA16(p1h, b2h[nt], aP[nt]);
            aP2[nt] = MFMA16(p1h, b2l[nt], aP2[nt]);
            aP2[nt] = MFMA16(p1l, b2h[nt], aP2[nt]);
        }
    }
    __syncthreads();  // stage_p reads done; p2t/rbt overwrite it

#pragma unroll
    for (int i = 0; i < 4; ++i) {
        int row = m0 + quad * 4 + i;  // 0..31
#pragma unroll
        for (int nt = 0; nt < 3; ++nt) {
            int col = n0t + nt * 16 + l16;
            float v2 = aP[nt][i] + aP2[nt][i] * (1.f / 2048.f) + bp2[col];
            float vr = aR[nt][i] + aR2[nt][i] * (1.f / 2048.f) + br1[col];
            p2t[row * 96 + col] = fmaxf(v2, 0.f);
            rbt[row * 96 + col] = fmaxf(vr, 0.f);
        }
    }
    __syncthreads();

    if (tid < 32) {
        int row = row0 + tid;
        if (row < M) {
            float a0 = 0.f, a1 = 0.f, rr = 0.f;
            const float* p = p2t + tid * 96;
            const float* r = rbt + tid * 96;
#pragma unroll
            for (int j = 0; j < 96; ++j) {
                a0 += p[j] * Wp3[j * 2 + 0];
                a1 += p[j] * Wp3[j * 2 + 1];
                rr += r[j] * Wr2[j];
            }
            a0 += bp3[0];
            a1 += bp3[1];
            rr += br2[0];
            float radius = 1.f / (1.f + expf(-rr));
            float nrm = sqrtf(a0 * a0 + a1 * a1) + 1e-8f;
            float sc = radius / nrm;
            out[(size_t)row * 2 + 0] = a0 * sc;
            out[(size_t)row * 2 + 1] = a1 * sc;
        }
    }
}

extern "C" void kernel_launch(void* const* d_in, const int* in_sizes, int n_in,
                              void* d_out, int out_size, void* d_ws, size_t ws_size,
                              hipStream_t stream) {
    const float* x     = (const float*)d_in[0];
    const int*   ei    = (const int*)d_in[1];
    const float* Wp    = (const float*)d_in[2];
    const float* bp    = (const float*)d_in[3];
    const float* convW = (const float*)d_in[4];
    const float* convB = (const float*)d_in[5];
    const float* Wp1   = (const float*)d_in[6];
    const float* bp1   = (const float*)d_in[7];
    const float* Wp2   = (const float*)d_in[8];
    const float* bp2   = (const float*)d_in[9];
    const float* Wp3   = (const float*)d_in[10];
    const float* bp3   = (const float*)d_in[11];
    const float* Wr1   = (const float*)d_in[12];
    const float* br1   = (const float*)d_in[13];
    const float* Wr2   = (const float*)d_in[14];
    const float* br2   = (const float*)d_in[15];
    float* out = (float*)d_out;

    const int M = in_sizes[0] / 128;  // 50000
    const int E = in_sizes[1] / 2;    // 800000
    const int* srcI = ei;
    const int* dstI = ei + E;
    const int RBp = (M + 31) / 32;    // 1563 32-row pages
    const int Mr  = RBp * 32;

    char* w = (char*)d_ws;
    size_t off = 0;
    auto alloc = [&](size_t b) { size_t o = off; off += (b + 255) & ~(size_t)255; return o; };
    short*         mscq = (short*)(w + alloc((size_t)Mr * 192 * 2));
    float*         mscs = (float*)(w + alloc((size_t)Mr * 4 * 4));
    _Float16*      hpkH = (_Float16*)(w + alloc((size_t)RBp * 6144 * 2));
    unsigned char* hpkL = (unsigned char*)(w + alloc((size_t)RBp * 6144));
    _Float16* WpPh  = (_Float16*)(w + alloc((size_t)128 * 192 * 2));
    _Float16* WpPl  = (_Float16*)(w + alloc((size_t)128 * 192 * 2));
    _Float16* cWPh  = (_Float16*)(w + alloc((size_t)4 * 192 * 192 * 2));
    _Float16* cWPl  = (_Float16*)(w + alloc((size_t)4 * 192 * 192 * 2));
    _Float16* Wp1Ph = (_Float16*)(w + alloc((size_t)192 * 192 * 2));
    _Float16* Wp1Pl = (_Float16*)(w + alloc((size_t)192 * 192 * 2));
    _Float16* Wp2Ph = (_Float16*)(w + alloc((size_t)192 * 96 * 2));
    _Float16* Wp2Pl = (_Float16*)(w + alloc((size_t)192 * 96 * 2));
    _Float16* Wr1Ph = (_Float16*)(w + alloc((size_t)192 * 96 * 2));
    _Float16* Wr1Pl = (_Float16*)(w + alloc((size_t)192 * 96 * 2));
    int*      cnt    = (int*)(w + alloc((size_t)M * 4));
    int*      cursor = (int*)(w + alloc((size_t)M * 4));
    float*    dinv   = (float*)(w + alloc((size_t)M * 4));
    int*      rowptr = (int*)(w + alloc((size_t)(M + 1) * 4));
    int*      csr    = (int*)(w + alloc((size_t)(E + 64) * 4));
    int*      bsum   = (int*)(w + alloc(256 * 4));
    int*      boff   = (int*)(w + alloc(256 * 4));

    hipMemsetAsync(cnt, 0, (size_t)((char*)cursor - (char*)cnt) + (size_t)M * 4, stream);

    // fused prep: count + pack_b
    const int nCount = (E + 255) / 256;
    WSegs segs;
    segs.s[0] = {Wp, WpPh, WpPl, 128, 192};
    segs.s[1] = {convW + 0 * 192 * 192, cWPh + 0 * 192 * 192, cWPl + 0 * 192 * 192, 192, 192};
    segs.s[2] = {convW + 1 * 192 * 192, cWPh + 1 * 192 * 192, cWPl + 1 * 192 * 192, 192, 192};
    segs.s[3] = {convW + 2 * 192 * 192, cWPh + 2 * 192 * 192, cWPl + 2 * 192 * 192, 192, 192};
    segs.s[4] = {convW + 3 * 192 * 192, cWPh + 3 * 192 * 192, cWPl + 3 * 192 * 192, 192, 192};
    segs.s[5] = {Wp1, Wp1Ph, Wp1Pl, 192, 192};
    segs.s[6] = {Wp2, Wp2Ph, Wp2Pl, 192, 96};
    segs.s[7] = {Wr1, Wr1Ph, Wr1Pl, 192, 96};
    prep_kernel<<<nCount + 8 * 144, 256, 0, stream>>>(dstI, E, cnt, segs, nCount);

    int nb = (M + 255) / 256;
    scan1_kernel<<<nb, 256, 0, stream>>>(cnt, M, rowptr, bsum, dinv);
    scan2_kernel<<<1, 256, 0, stream>>>(bsum, nb, boff);
    scan3_kernel<<<(M + 256) / 256, 256, 0, stream>>>(rowptr, M, E, boff);
    fill_kernel<<<(E + 255) / 256, 256, 0, stream>>>(srcI, dstI, E, rowptr, cursor, csr);

    // HEAD: x -> h1 (planes) -> msc0
    head_kernel<<<RBp, 256, 0, stream>>>(
        x, WpPh, WpPl, bp, cWPh, cWPl, dinv, hpkH, hpkL, mscq, mscs, M);
    // 4 GCN layers: standalone wave-per-node aggregate; conv GEMM between
    for (int i = 0; i < 4; i++) {
        aggregate_kernel<<<(M + 3) / 4, 256, 0, stream>>>(
            mscq, mscs, csr, rowptr, dinv, convB + (size_t)i * 192, hpkH, hpkL, M);
        if (i < 3)
            conv_gemm_kernel<<<RBp, 256, 0, stream>>>(
                hpkH, hpkL, cWPh + (size_t)(i + 1) * 36864, cWPl + (size_t)(i + 1) * 36864,
                dinv, mscq, mscs, M);
    }
    // TAIL: p1+r (one h read) + p2 + finalize
    tail_kernel<<<RBp, 256, 0, stream>>>(
        hpkH, hpkL, Wp1Ph, Wp1Pl, bp1, Wp2Ph, Wp2Pl, Wr1Ph, Wr1Pl, bp2, br1,
        Wp3, bp3, Wr2, br2, out, M);
}

// Round 6
// 568.471 us; speedup vs baseline: 1.0543x; 1.0543x over previous
//
#include <hip/hip_runtime.h>
#include <math.h>

typedef __attribute__((ext_vector_type(8))) _Float16 f16x8;
typedef __attribute__((ext_vector_type(4))) _Float16 f16x4;
typedef __attribute__((ext_vector_type(4))) float f32x4;
typedef __attribute__((ext_vector_type(4))) short s16x4;

#define MFMA16(a, b, c) __builtin_amdgcn_mfma_f32_16x16x32_f16(a, b, c, 0, 0, 0)

// ---------------------------------------------------------------------------
// Precision: GEMMs split-fp16 (a = ah + al/2048) ~2^-22 rel. msc int16 with
// per-(row,48-block) fp32 scale (~1.5e-5). h stored fp16-hi + e5m2-lo
// (x2048) planes = 3 B/feature (~6e-5/event). Radius GEMM fp16-only
// weights (sigmoid path, derivative <=0.25, not direction-amplified):
// ~+1e-3 worst. Measured r16 absmax 0.0039; predicted <=0.005 vs 1.9e-2.
//
// Round 17: tail structural fix. r15/r16 proved tail is NOT decode-bound
// (e4m3 vs e5m2 both 62% VALUBusy): the cost is the serial spine --
// p2t/rbt LDS round-trip + 32-thread serial 96-iter finalize with
// stride-96 (32-way) bank conflicts (1.35M/dispatch). Replaced by
// in-register projection (pos = p2@Wp3, rr = r@Wr2 done per-thread on
// accumulators) + 4-step shfl_xor butterfly over the quad group + 384 B
// LDS to join the two col-halves. Radius GEMM drops its lo plane.
// Aggregate (r14) / conv / head frozen.
// ---------------------------------------------------------------------------

__device__ __forceinline__ unsigned char enc_e5m2(float x) {
    unsigned short b = __builtin_bit_cast(unsigned short, (_Float16)x);
    b = (unsigned short)(b + 0x80);  // round mantissa to 2 bits
    return (unsigned char)(b >> 8);
}
__device__ __forceinline__ f16x8 dec8(uint2 w) {
    unsigned int r0 = ((w.x & 0x000000FFu) << 8) | ((w.x & 0x0000FF00u) << 16);
    unsigned int r1 = ((w.x >> 8) & 0x0000FF00u) | (w.x & 0xFF000000u);
    unsigned int r2 = ((w.y & 0x000000FFu) << 8) | ((w.y & 0x0000FF00u) << 16);
    unsigned int r3 = ((w.y >> 8) & 0x0000FF00u) | (w.y & 0xFF000000u);
    uint4 u = {r0, r1, r2, r3};
    return __builtin_bit_cast(f16x8, u);
}
__device__ __forceinline__ f16x4 dec4(unsigned int w) {
    unsigned int r0 = ((w & 0x000000FFu) << 8) | ((w & 0x0000FF00u) << 16);
    unsigned int r1 = ((w >> 8) & 0x0000FF00u) | (w & 0xFF000000u);
    uint2 u = {r0, r1};
    return __builtin_bit_cast(f16x4, u);
}

// ------------------------- graph setup -------------------------------------
__global__ void scan1_kernel(const int* __restrict__ cnt, int M,
                             int* __restrict__ rowptr, int* __restrict__ bsum,
                             float* __restrict__ dinv) {
    __shared__ int s[256];
    int t = threadIdx.x;
    int i = blockIdx.x * 256 + t;
    int v = (i < M) ? cnt[i] : 0;
    s[t] = v; __syncthreads();
    for (int o = 1; o < 256; o <<= 1) {
        int x = (t >= o) ? s[t - o] : 0;
        __syncthreads();
        s[t] += x;
        __syncthreads();
    }
    if (i < M) {
        rowptr[i] = s[t] - v;
        dinv[i] = rsqrtf((float)v + 1.0f);  // deg = in-deg + self-loop
    }
    if (t == 255) bsum[blockIdx.x] = s[255];
}

__global__ void scan2_kernel(const int* __restrict__ bsum, int nb, int* __restrict__ boff) {
    __shared__ int s[256];
    int t = threadIdx.x;
    int v = (t < nb) ? bsum[t] : 0;
    s[t] = v; __syncthreads();
    for (int o = 1; o < 256; o <<= 1) {
        int x = (t >= o) ? s[t - o] : 0;
        __syncthreads();
        s[t] += x;
        __syncthreads();
    }
    if (t < nb) boff[t] = s[t] - v;
}

__global__ void scan3_kernel(int* __restrict__ rowptr, int M, int E, const int* __restrict__ boff) {
    int i = blockIdx.x * 256 + threadIdx.x;
    if (i < M) rowptr[i] += boff[blockIdx.x];
    if (i == M) rowptr[M] = E;
}

__global__ void fill_kernel(const int* __restrict__ src, const int* __restrict__ dst, int E,
                            const int* __restrict__ rowptr, int* __restrict__ cursor,
                            int* __restrict__ csr) {
    int i = blockIdx.x * blockDim.x + threadIdx.x;
    if (i < E) {
        int d = dst[i];
        int slot = atomicAdd(&cursor[d], 1);
        csr[rowptr[d] + slot] = src[i];
    }
}

// ---------------- fused prep: count + pack_b --------------------------------
struct WSeg { const float* src; _Float16* dh; _Float16* dl; int K; int N; };
struct WSegs { WSeg s[8]; };

__global__ void prep_kernel(const int* __restrict__ dst, int E, int* __restrict__ cnt,
                            WSegs segs, int nCount) {
    int b = blockIdx.x;
    if (b < nCount) {
        int i = b * 256 + threadIdx.x;
        if (i < E) atomicAdd(&cnt[dst[i]], 1);
        return;
    }
    b -= nCount;
    // pack_b: frag-major WT planes, flat i = ((s*G+g)*64+l)*8+j
    WSeg sg = segs.s[b / 144];
    int i = (b % 144) * 256 + threadIdx.x;
    if (i >= sg.K * sg.N) return;
    int G = sg.N >> 4;
    int s = i / (G * 512);
    int r = i - s * (G * 512);
    int g = r >> 9;
    int r2 = r & 511;
    int l = r2 >> 3, j = r2 & 7;
    int n = g * 16 + (l & 15);
    int k = s * 32 + (l >> 4) * 8 + j;
    float w = sg.src[(size_t)k * sg.N + n];
    _Float16 hi = (_Float16)w;
    sg.dh[i] = hi;
    if (sg.dl) sg.dl[i] = (_Float16)((w - (float)hi) * 2048.f);
}

// ---------------------------------------------------------------------------
// Shared GEMM epilogue (NN=192, 4 waves x 48 cols, C/D col=lane&15,
// row=quad*4+reg). OM bit0: int16+scale msc out. OM bit1: global h planes
// (fp16 hi + e5m2 lo). OM bit2: LDS pair-format stage (page-local).
// h plane layout: [page][slab s=col>>5][row 0..31][32], elem (kk=col&31):
// chunk c=kk>>3 stored at slot ph=c^(row&3), j=kk&7.
// ---------------------------------------------------------------------------
template <int ACT, int OM>
__device__ __forceinline__ void epi192(
    f32x4 (&acc)[2][3], f32x4 (&acc2)[2][3],
    const float* __restrict__ bias, const float* __restrict__ rowscale,
    short* __restrict__ Cq, float* __restrict__ Cs,
    _Float16* __restrict__ ChH, unsigned char* __restrict__ ChL,
    _Float16* CpL,
    int row0, int M) {
    const int tid = threadIdx.x;
    const int wave = tid >> 6, lane = tid & 63;
    const int quad = lane >> 4, l16 = lane & 15;
    const int n0 = wave * 48;
    float bv[3];
#pragma unroll
    for (int nt = 0; nt < 3; ++nt) bv[nt] = bias ? bias[n0 + nt * 16 + l16] : 0.f;
#pragma unroll
    for (int mt = 0; mt < 2; ++mt)
#pragma unroll
        for (int i = 0; i < 4; ++i) {
            int rl = mt * 16 + quad * 4 + i;
            int row = row0 + rl;
            bool ok = row < M;
            float v[3] = {0.f, 0.f, 0.f};
            if (ok) {
                float rs = rowscale ? rowscale[row] : 1.f;
#pragma unroll
                for (int nt = 0; nt < 3; ++nt) {
                    float t = acc[mt][nt][i] + acc2[mt][nt][i] * (1.f / 2048.f) + bv[nt];
                    if (ACT == 1) t = fmaxf(t, 0.f);
                    v[nt] = t * rs;
                }
            }
            if (OM & 1) {
                if (ok) {
                    // row-block max: the 16 lanes of this quad hold this
                    // row's 48 cols (3 regs each) -> butterfly, no LDS.
                    float m = fmaxf(fmaxf(fabsf(v[0]), fabsf(v[1])), fabsf(v[2]));
#pragma unroll
                    for (int d = 1; d < 16; d <<= 1) m = fmaxf(m, __shfl_xor(m, d));
                    float inv = (m > 0.f) ? 32767.f / m : 0.f;
#pragma unroll
                    for (int nt = 0; nt < 3; ++nt) {
                        int col = n0 + nt * 16 + l16;
                        Cq[(size_t)row * 192 + col] = (short)rintf(v[nt] * inv);
                    }
                    if (l16 == 0) Cs[row * 4 + wave] = m * (1.f / 32767.f);
                }
            }
            if (OM & 6) {
#pragma unroll
                for (int nt = 0; nt < 3; ++nt) {
                    int col = n0 + nt * 16 + l16;
                    _Float16 hi = (_Float16)v[nt];
                    float lof = (v[nt] - (float)hi) * 2048.f;
                    if (OM & 2) {
                        if (ok) {
                            int s = col >> 5, kk = col & 31;
                            int ph = (kk >> 3) ^ (rl & 3), j = kk & 7;
                            size_t base = ((size_t)((row >> 5) * 6 + s) * 32 + (row & 31)) * 32 + ph * 8 + j;
                            ChH[base] = hi;
                            ChL[base] = enc_e5m2(lof);
                        }
                    }
                    if (OM & 4) {
                        int os = col >> 5, ocn = (col >> 3) & 3, j = col & 7;
                        int ph2 = ocn ^ (rl & 7);
                        int baseL = (os * 32 + rl) * 64;
                        CpL[baseL + ph2 * 8 + j] = hi;
                        CpL[baseL + (ph2 ^ 4) * 8 + j] = (_Float16)lof;
                    }
                }
            }
        }
}

// GEMM K=192. AF=0: A is a pair-format page (LDS stage, 64 f16/row-slab).
// AF=1: A is global hi/lo planes (fp16 + e5m2, 32/row-slab each).
template <int ACT, int OM, int AF>
__device__ __forceinline__ void gemm192(
    const _Float16* Ah_, const unsigned char* Al_,
    const _Float16* __restrict__ Bph, const _Float16* __restrict__ Bpl,
    const float* __restrict__ bias, const float* __restrict__ rowscale,
    short* __restrict__ Cq, float* __restrict__ Cs,
    _Float16* __restrict__ ChH, unsigned char* __restrict__ ChL,
    _Float16* CpL,
    int row0, int M) {
    const int tid = threadIdx.x;
    const int wave = tid >> 6, lane = tid & 63;
    const int quad = lane >> 4, l16 = lane & 15;
    const int g0 = (wave * 48) >> 4;
    f32x4 acc[2][3], acc2[2][3];
#pragma unroll
    for (int mt = 0; mt < 2; ++mt)
#pragma unroll
        for (int nt = 0; nt < 3; ++nt) {
            acc[mt][nt] = (f32x4){0.f, 0.f, 0.f, 0.f};
            acc2[mt][nt] = (f32x4){0.f, 0.f, 0.f, 0.f};
        }
#pragma unroll
    for (int s = 0; s < 6; ++s) {
        f16x8 ah[2], al[2];
#pragma unroll
        for (int mt = 0; mt < 2; ++mt) {
            int R = mt * 16 + l16;
            if (AF == 0) {
                int ph = quad ^ (R & 7);
                ah[mt] = *reinterpret_cast<const f16x8*>(Ah_ + s * 2048 + R * 64 + ph * 8);
                al[mt] = *reinterpret_cast<const f16x8*>(Ah_ + s * 2048 + R * 64 + (ph ^ 4) * 8);
            } else {
                int ph = quad ^ (R & 3);
                size_t o = (size_t)s * 1024 + R * 32 + ph * 8;
                ah[mt] = *reinterpret_cast<const f16x8*>(Ah_ + o);
                al[mt] = dec8(*reinterpret_cast<const uint2*>(Al_ + o));
            }
        }
        f16x8 bh[3], bl[3];
#pragma unroll
        for (int nt = 0; nt < 3; ++nt) {
            size_t o = ((size_t)(s * 12 + g0 + nt) * 64 + lane) * 8;
            bh[nt] = *reinterpret_cast<const f16x8*>(Bph + o);
            bl[nt] = *reinterpret_cast<const f16x8*>(Bpl + o);
        }
#pragma unroll
        for (int mt = 0; mt < 2; ++mt)
#pragma unroll
            for (int nt = 0; nt < 3; ++nt) {
                acc[mt][nt] = MFMA16(ah[mt], bh[nt], acc[mt][nt]);
                acc2[mt][nt] = MFMA16(ah[mt], bl[nt], acc2[mt][nt]);
                acc2[mt][nt] = MFMA16(al[mt], bh[nt], acc2[mt][nt]);
            }
    }
    epi192<ACT, OM>(acc, acc2, bias, rowscale, Cq, Cs, ChH, ChL, CpL, row0, M);
}

// ---------------------------------------------------------------------------
// HEAD: h1 = x@Wp + bp (x direct f32 loads) -> global h planes + LDS pair
// stage; msc0 = (h1@W0)*dinv -> int16+scale.
// ---------------------------------------------------------------------------
__global__ __launch_bounds__(256, 4) void head_kernel(
    const float* __restrict__ x,
    const _Float16* __restrict__ WpPh, const _Float16* __restrict__ WpPl,
    const float* __restrict__ bp,
    const _Float16* __restrict__ W0h, const _Float16* __restrict__ W0l,
    const float* __restrict__ dinv,
    _Float16* __restrict__ hH, unsigned char* __restrict__ hL,
    short* __restrict__ mscq, float* __restrict__ mscs,
    int M) {
    __shared__ __align__(16) _Float16 stage[6 * 2048];
    const int tid = threadIdx.x;
    const int wave = tid >> 6, lane = tid & 63;
    const int quad = lane >> 4, l16 = lane & 15;
    const int g0 = (wave * 48) >> 4;
    const int row0 = blockIdx.x * 32;

    f32x4 acc[2][3], acc2[2][3];
#pragma unroll
    for (int mt = 0; mt < 2; ++mt)
#pragma unroll
        for (int nt = 0; nt < 3; ++nt) {
            acc[mt][nt] = (f32x4){0.f, 0.f, 0.f, 0.f};
            acc2[mt][nt] = (f32x4){0.f, 0.f, 0.f, 0.f};
        }
#pragma unroll
    for (int s = 0; s < 4; ++s) {  // KK=128 -> 4 slabs
        f16x8 ah[2], al[2];
#pragma unroll
        for (int mt = 0; mt < 2; ++mt) {
            int R = mt * 16 + l16, row = row0 + R;
            f32x4 xa = (f32x4){0.f, 0.f, 0.f, 0.f}, xb = xa;
            if (row < M) {
                const float* xr = x + (size_t)row * 128 + s * 32 + quad * 8;
                xa = *reinterpret_cast<const f32x4*>(xr);
                xb = *reinterpret_cast<const f32x4*>(xr + 4);
            }
#pragma unroll
            for (int j = 0; j < 4; ++j) {
                _Float16 ha = (_Float16)xa[j], hb = (_Float16)xb[j];
                ah[mt][j] = ha; ah[mt][j + 4] = hb;
                al[mt][j] = (_Float16)((xa[j] - (float)ha) * 2048.f);
                al[mt][j + 4] = (_Float16)((xb[j] - (float)hb) * 2048.f);
            }
        }
        f16x8 bh[3], bl[3];
#pragma unroll
        for (int nt = 0; nt < 3; ++nt) {
            size_t o = ((size_t)(s * 12 + g0 + nt) * 64 + lane) * 8;
            bh[nt] = *reinterpret_cast<const f16x8*>(WpPh + o);
            bl[nt] = *reinterpret_cast<const f16x8*>(WpPl + o);
        }
#pragma unroll
        for (int mt = 0; mt < 2; ++mt)
#pragma unroll
            for (int nt = 0; nt < 3; ++nt) {
                acc[mt][nt] = MFMA16(ah[mt], bh[nt], acc[mt][nt]);
                acc2[mt][nt] = MFMA16(ah[mt], bl[nt], acc2[mt][nt]);
                acc2[mt][nt] = MFMA16(al[mt], bh[nt], acc2[mt][nt]);
            }
    }
    epi192<0, 6>(acc, acc2, bp, nullptr, nullptr, nullptr, hH, hL, stage, row0, M);
    __syncthreads();
    gemm192<0, 1, 0>(stage, nullptr, W0h, W0l, nullptr, dinv,
                     mscq, mscs, nullptr, nullptr, nullptr, row0, M);
}

// ---------------------------------------------------------------------------
// conv GEMM: msc = (h@W)*dinv -> int16+scale. A read from global h planes.
// ---------------------------------------------------------------------------
__global__ __launch_bounds__(256, 4) void conv_gemm_kernel(
    const _Float16* __restrict__ hH, const unsigned char* __restrict__ hL,
    const _Float16* __restrict__ Bh, const _Float16* __restrict__ Bl,
    const float* __restrict__ dinv,
    short* __restrict__ mq, float* __restrict__ ms, int M) {
    gemm192<0, 1, 1>(hH + (size_t)blockIdx.x * 6144, hL + (size_t)blockIdx.x * 6144,
                     Bh, Bl, nullptr, dinv, mq, ms, nullptr, nullptr, nullptr,
                     blockIdx.x * 32, M);
}

// ---------------------------------------------------------------------------
// int16 whole-row aggregation (r14 structure: wave-per-node, 4-chain ILP).
// h RMW on fp16+e5m2 planes. h = h + relu(dinv[n]*sum + B).
// ---------------------------------------------------------------------------
__global__ __launch_bounds__(256) void aggregate_kernel(
    const short* __restrict__ mscq, const float* __restrict__ mscs,
    const int* __restrict__ csr, const int* __restrict__ rowptr,
    const float* __restrict__ dinv, const float* __restrict__ bias,
    _Float16* __restrict__ hH, unsigned char* __restrict__ hL, int M) {
    int wid = (blockIdx.x * 256 + threadIdx.x) >> 6;
    int lane = threadIdx.x & 63;
    if (wid >= M || lane >= 48) return;
    const int soff = lane / 12;
    const int f0 = lane * 4;

    // self-loop term
    s16x4 q0 = *reinterpret_cast<const s16x4*>(mscq + (size_t)wid * 192 + f0);
    float f0v = mscs[wid * 4 + soff];
    float4 a0, a1, a2, a3;
    a0.x = (float)q0[0] * f0v; a0.y = (float)q0[1] * f0v;
    a0.z = (float)q0[2] * f0v; a0.w = (float)q0[3] * f0v;
    a1 = make_float4(0.f, 0.f, 0.f, 0.f);
    a2 = a1; a3 = a1;

    int beg = rowptr[wid], end = rowptr[wid + 1];
    int e = beg;
    for (; e + 3 < end; e += 4) {
        int sa = csr[e], sb = csr[e + 1], sc = csr[e + 2], sd = csr[e + 3];
        s16x4 qa = *reinterpret_cast<const s16x4*>(mscq + (size_t)sa * 192 + f0);
        float fa = mscs[sa * 4 + soff];
        s16x4 qb = *reinterpret_cast<const s16x4*>(mscq + (size_t)sb * 192 + f0);
        float fb = mscs[sb * 4 + soff];
        s16x4 qc = *reinterpret_cast<const s16x4*>(mscq + (size_t)sc * 192 + f0);
        float fc = mscs[sc * 4 + soff];
        s16x4 qd = *reinterpret_cast<const s16x4*>(mscq + (size_t)sd * 192 + f0);
        float fd = mscs[sd * 4 + soff];
        a0.x = fmaf((float)qa[0], fa, a0.x);
        a0.y = fmaf((float)qa[1], fa, a0.y);
        a0.z = fmaf((float)qa[2], fa, a0.z);
        a0.w = fmaf((float)qa[3], fa, a0.w);
        a1.x = fmaf((float)qb[0], fb, a1.x);
        a1.y = fmaf((float)qb[1], fb, a1.y);
        a1.z = fmaf((float)qb[2], fb, a1.z);
        a1.w = fmaf((float)qb[3], fb, a1.w);
        a2.x = fmaf((float)qc[0], fc, a2.x);
        a2.y = fmaf((float)qc[1], fc, a2.y);
        a2.z = fmaf((float)qc[2], fc, a2.z);
        a2.w = fmaf((float)qc[3], fc, a2.w);
        a3.x = fmaf((float)qd[0], fd, a3.x);
        a3.y = fmaf((float)qd[1], fd, a3.y);
        a3.z = fmaf((float)qd[2], fd, a3.z);
        a3.w = fmaf((float)qd[3], fd, a3.w);
    }
    for (; e + 1 < end; e += 2) {
        int sa = csr[e], sb = csr[e + 1];
        s16x4 qa = *reinterpret_cast<const s16x4*>(mscq + (size_t)sa * 192 + f0);
        float fa = mscs[sa * 4 + soff];
        s16x4 qb = *reinterpret_cast<const s16x4*>(mscq + (size_t)sb * 192 + f0);
        float fb = mscs[sb * 4 + soff];
        a0.x = fmaf((float)qa[0], fa, a0.x);
        a0.y = fmaf((float)qa[1], fa, a0.y);
        a0.z = fmaf((float)qa[2], fa, a0.z);
        a0.w = fmaf((float)qa[3], fa, a0.w);
        a1.x = fmaf((float)qb[0], fb, a1.x);
        a1.y = fmaf((float)qb[1], fb, a1.y);
        a1.z = fmaf((float)qb[2], fb, a1.z);
        a1.w = fmaf((float)qb[3], fb, a1.w);
    }
    if (e < end) {
        int sa = csr[e];
        s16x4 qa = *reinterpret_cast<const s16x4*>(mscq + (size_t)sa * 192 + f0);
        float fa = mscs[sa * 4 + soff];
        a0.x = fmaf((float)qa[0], fa, a0.x);
        a0.y = fmaf((float)qa[1], fa, a0.y);
        a0.z = fmaf((float)qa[2], fa, a0.z);
        a0.w = fmaf((float)qa[3], fa, a0.w);
    }
    float4 a;
    a.x = (a0.x + a1.x) + (a2.x + a3.x);
    a.y = (a0.y + a1.y) + (a2.y + a3.y);
    a.z = (a0.z + a1.z) + (a2.z + a3.z);
    a.w = (a0.w + a1.w) + (a2.w + a3.w);

    float dn = dinv[wid];
    float4 b = reinterpret_cast<const float4*>(bias)[lane];

    // h plane granule for features f0 = lane*4 .. +4
    int s = f0 >> 5, kk = f0 & 31;
    int r = wid & 31;
    int ph = (kk >> 3) ^ (r & 3), j = f0 & 7;
    size_t hb = ((size_t)((wid >> 5) * 6 + s) * 32 + r) * 32 + ph * 8 + j;
    f16x4* hp = reinterpret_cast<f16x4*>(hH + hb);
    unsigned int* lp = reinterpret_cast<unsigned int*>(hL + hb);
    f16x4 hh = *hp;
    f16x4 hl = dec4(*lp);
    float4 hv;
    hv.x = (float)hh[0] + (float)hl[0] * (1.f / 2048.f) + fmaxf(a.x * dn + b.x, 0.f);
    hv.y = (float)hh[1] + (float)hl[1] * (1.f / 2048.f) + fmaxf(a.y * dn + b.y, 0.f);
    hv.z = (float)hh[2] + (float)hl[2] * (1.f / 2048.f) + fmaxf(a.z * dn + b.z, 0.f);
    hv.w = (float)hh[3] + (float)hl[3] * (1.f / 2048.f) + fmaxf(a.w * dn + b.w, 0.f);
    f16x4 nh = {(_Float16)hv.x, (_Float16)hv.y, (_Float16)hv.z, (_Float16)hv.w};
    unsigned char b0 = enc_e5m2((hv.x - (float)nh[0]) * 2048.f);
    unsigned char b1 = enc_e5m2((hv.y - (float)nh[1]) * 2048.f);
    unsigned char b2 = enc_e5m2((hv.z - (float)nh[2]) * 2048.f);
    unsigned char b3 = enc_e5m2((hv.w - (float)nh[3]) * 2048.f);
    *hp = nh;
    *lp = (unsigned int)b0 | ((unsigned int)b1 << 8) |
          ((unsigned int)b2 << 16) | ((unsigned int)b3 << 24);
}

// ---------------------------------------------------------------------------
// TAIL: s-loop 1 computes p1 = relu(h@Wp1+bp1) [split] AND
// r = relu(h@Wr1+br1) [fp16-only weights] with ONE h read. p1 -> LDS pair
// stage; p2 = relu(p1@Wp2+bp2) [split]. Finalize is IN-REGISTER: each
// thread projects its 12 accumulator values onto Wp3/Wr2, butterfly-
// reduces over the 16-lane quad group, joins the two col-halves via
// 384 B of LDS (aliasing stage_p after its reads complete).
// ---------------------------------------------------------------------------
__global__ __launch_bounds__(256, 4) void tail_kernel(
    const _Float16* __restrict__ hH, const unsigned char* __restrict__ hL,
    const _Float16* __restrict__ W1h, const _Float16* __restrict__ W1l,
    const float* __restrict__ bp1,
    const _Float16* __restrict__ W2h, const _Float16* __restrict__ W2l,
    const _Float16* __restrict__ Wrh,
    const float* __restrict__ bp2, const float* __restrict__ br1,
    const float* __restrict__ Wp3, const float* __restrict__ bp3,
    const float* __restrict__ Wr2, const float* __restrict__ br2,
    float* __restrict__ out, int M) {
    __shared__ __align__(16) _Float16 stage_p[6 * 2048];
    float* red = reinterpret_cast<float*>(stage_p);  // 32*3 f32 alias, post-p2
    const int tid = threadIdx.x;
    const int wave = tid >> 6, lane = tid & 63;
    const int quad = lane >> 4, l16 = lane & 15;
    const int g0 = (wave * 48) >> 4;     // p1 cols (N=192)
    const int m0 = (wave >> 1) * 16;     // p2/r m-half
    const int n0t = (wave & 1) * 48;     // p2/r n-half (N=96)
    const int g0t = n0t >> 4;
    const int wh = wave >> 1;
    const int row0 = blockIdx.x * 32;
    const _Float16* hpH = hH + (size_t)blockIdx.x * 6144;
    const unsigned char* hpL = hL + (size_t)blockIdx.x * 6144;

    f32x4 aB[2][3], aB2[2][3], aR[3];
#pragma unroll
    for (int nt = 0; nt < 3; ++nt) {
        aR[nt] = (f32x4){0.f, 0.f, 0.f, 0.f};
#pragma unroll
        for (int mt = 0; mt < 2; ++mt) { aB[mt][nt] = aR[nt]; aB2[mt][nt] = aR[nt]; }
    }

#pragma unroll
    for (int s = 0; s < 6; ++s) {
        f16x8 ah[2], al[2];
#pragma unroll
        for (int mt = 0; mt < 2; ++mt) {
            int R = mt * 16 + l16;
            int ph = quad ^ (R & 3);
            size_t o = (size_t)s * 1024 + R * 32 + ph * 8;
            ah[mt] = *reinterpret_cast<const f16x8*>(hpH + o);
            al[mt] = dec8(*reinterpret_cast<const uint2*>(hpL + o));
        }
        {   // p1 GEMM (N=192, split)
            f16x8 b1h[3], b1l[3];
#pragma unroll
            for (int nt = 0; nt < 3; ++nt) {
                size_t o = ((size_t)(s * 12 + g0 + nt) * 64 + lane) * 8;
                b1h[nt] = *reinterpret_cast<const f16x8*>(W1h + o);
                b1l[nt] = *reinterpret_cast<const f16x8*>(W1l + o);
            }
#pragma unroll
            for (int mt = 0; mt < 2; ++mt)
#pragma unroll
                for (int nt = 0; nt < 3; ++nt) {
                    aB[mt][nt] = MFMA16(ah[mt], b1h[nt], aB[mt][nt]);
                    aB2[mt][nt] = MFMA16(ah[mt], b1l[nt], aB2[mt][nt]);
                    aB2[mt][nt] = MFMA16(al[mt], b1h[nt], aB2[mt][nt]);
                }
        }
        {   // r GEMM (N=96, fp16-only) reusing ah[wh]
            f16x8 brh[3];
#pragma unroll
            for (int nt = 0; nt < 3; ++nt) {
                size_t o = ((size_t)(s * 6 + g0t + nt) * 64 + lane) * 8;
                brh[nt] = *reinterpret_cast<const f16x8*>(Wrh + o);
            }
#pragma unroll
            for (int nt = 0; nt < 3; ++nt)
                aR[nt] = MFMA16(ah[wh], brh[nt], aR[nt]);
        }
    }
    epi192<1, 4>(aB, aB2, bp1, nullptr, nullptr, nullptr, nullptr, nullptr,
                 stage_p, row0, M);
    __syncthreads();

    // p2 GEMM (N=96, split) from stage_p
    f32x4 aP[3], aP2[3];
#pragma unroll
    for (int nt = 0; nt < 3; ++nt) {
        aP[nt] = (f32x4){0.f, 0.f, 0.f, 0.f};
        aP2[nt] = aP[nt];
    }
#pragma unroll
    for (int s = 0; s < 6; ++s) {
        const int R = m0 + l16;
        const int ph = quad ^ (R & 7);
        f16x8 p1h = *reinterpret_cast<const f16x8*>(stage_p + s * 2048 + R * 64 + ph * 8);
        f16x8 p1l = *reinterpret_cast<const f16x8*>(stage_p + s * 2048 + R * 64 + (ph ^ 4) * 8);
        f16x8 b2h[3], b2l[3];
#pragma unroll
        for (int nt = 0; nt < 3; ++nt) {
            size_t o = ((size_t)(s * 6 + g0t + nt) * 64 + lane) * 8;
            b2h[nt] = *reinterpret_cast<const f16x8*>(W2h + o);
            b2l[nt] = *reinterpret_cast<const f16x8*>(W2l + o);
        }
#pragma unroll
        for (int nt = 0; nt < 3; ++nt) {
            aP[nt] = MFMA16(p1h, b2h[nt], aP[nt]);
            aP2[nt] = MFMA16(p1h, b2l[nt], aP2[nt]);
            aP2[nt] = MFMA16(p1l, b2h[nt], aP2[nt]);
        }
    }

    // ---- in-register finalize ----
    // weights for this thread's 3 cols (uniform over quad, i)
    float w30[3], w31[3], wr[3], b2v[3], brv[3];
#pragma unroll
    for (int nt = 0; nt < 3; ++nt) {
        int col = n0t + nt * 16 + l16;
        w30[nt] = Wp3[col * 2 + 0];
        w31[nt] = Wp3[col * 2 + 1];
        wr[nt] = Wr2[col];
        b2v[nt] = bp2[col];
        brv[nt] = br1[col];
    }
    float s0[4], s1[4], sr[4];
#pragma unroll
    for (int i = 0; i < 4; ++i) {
        float t0 = 0.f, t1 = 0.f, tr = 0.f;
#pragma unroll
        for (int nt = 0; nt < 3; ++nt) {
            float p2v = fmaxf(aP[nt][i] + aP2[nt][i] * (1.f / 2048.f) + b2v[nt], 0.f);
            float rv = fmaxf(aR[nt][i] + brv[nt], 0.f);
            t0 = fmaf(p2v, w30[nt], t0);
            t1 = fmaf(p2v, w31[nt], t1);
            tr = fmaf(rv, wr[nt], tr);
        }
        // 16-lane butterfly within the quad group
#pragma unroll
        for (int d = 1; d < 16; d <<= 1) {
            t0 += __shfl_xor(t0, d);
            t1 += __shfl_xor(t1, d);
            tr += __shfl_xor(tr, d);
        }
        s0[i] = t0; s1[i] = t1; sr[i] = tr;
    }
    __syncthreads();  // all stage_p reads complete before alias write
    if ((wave & 1) == 1 && l16 == 0) {
#pragma unroll
        for (int i = 0; i < 4; ++i) {
            int rl = m0 + quad * 4 + i;
            red[rl * 3 + 0] = s0[i];
            red[rl * 3 + 1] = s1[i];
            red[rl * 3 + 2] = sr[i];
        }
    }
    __syncthreads();
    if ((wave & 1) == 0 && l16 == 0) {
#pragma unroll
        for (int i = 0; i < 4; ++i) {
            int rl = m0 + quad * 4 + i;
            int row = row0 + rl;
            if (row < M) {
                float a0 = s0[i] + red[rl * 3 + 0] + bp3[0];
                float a1 = s1[i] + red[rl * 3 + 1] + bp3[1];
                float rr = sr[i] + red[rl * 3 + 2] + br2[0];
                float radius = 1.f / (1.f + expf(-rr));
                float nrm = sqrtf(a0 * a0 + a1 * a1) + 1e-8f;
                float sc = radius / nrm;
                out[(size_t)row * 2 + 0] = a0 * sc;
                out[(size_t)row * 2 + 1] = a1 * sc;
            }
        }
    }
}

extern "C" void kernel_launch(void* const* d_in, const int* in_sizes, int n_in,
                              void* d_out, int out_size, void* d_ws, size_t ws_size,
                              hipStream_t stream) {
    const float* x     = (const float*)d_in[0];
    const int*   ei    = (const int*)d_in[1];
    const float* Wp    = (const float*)d_in[2];
    const float* bp    = (const float*)d_in[3];
    const float* convW = (const float*)d_in[4];
    const float* convB = (const float*)d_in[5];
    const float* Wp1   = (const float*)d_in[6];
    const float* bp1   = (const float*)d_in[7];
    const float* Wp2   = (const float*)d_in[8];
    const float* bp2   = (const float*)d_in[9];
    const float* Wp3   = (const float*)d_in[10];
    const float* bp3   = (const float*)d_in[11];
    const float* Wr1   = (const float*)d_in[12];
    const float* br1   = (const float*)d_in[13];
    const float* Wr2   = (const float*)d_in[14];
    const float* br2   = (const float*)d_in[15];
    float* out = (float*)d_out;

    const int M = in_sizes[0] / 128;  // 50000
    const int E = in_sizes[1] / 2;    // 800000
    const int* srcI = ei;
    const int* dstI = ei + E;
    const int RBp = (M + 31) / 32;    // 1563 32-row pages
    const int Mr  = RBp * 32;

    char* w = (char*)d_ws;
    size_t off = 0;
    auto alloc = [&](size_t b) { size_t o = off; off += (b + 255) & ~(size_t)255; return o; };
    short*         mscq = (short*)(w + alloc((size_t)Mr * 192 * 2));
    float*         mscs = (float*)(w + alloc((size_t)Mr * 4 * 4));
    _Float16*      hpkH = (_Float16*)(w + alloc((size_t)RBp * 6144 * 2));
    unsigned char* hpkL = (unsigned char*)(w + alloc((size_t)RBp * 6144));
    _Float16* WpPh  = (_Float16*)(w + alloc((size_t)128 * 192 * 2));
    _Float16* WpPl  = (_Float16*)(w + alloc((size_t)128 * 192 * 2));
    _Float16* cWPh  = (_Float16*)(w + alloc((size_t)4 * 192 * 192 * 2));
    _Float16* cWPl  = (_Float16*)(w + alloc((size_t)4 * 192 * 192 * 2));
    _Float16* Wp1Ph = (_Float16*)(w + alloc((size_t)192 * 192 * 2));
    _Float16* Wp1Pl = (_Float16*)(w + alloc((size_t)192 * 192 * 2));
    _Float16* Wp2Ph = (_Float16*)(w + alloc((size_t)192 * 96 * 2));
    _Float16* Wp2Pl = (_Float16*)(w + alloc((size_t)192 * 96 * 2));
    _Float16* Wr1Ph = (_Float16*)(w + alloc((size_t)192 * 96 * 2));
    int*      cnt    = (int*)(w + alloc((size_t)M * 4));
    int*      cursor = (int*)(w + alloc((size_t)M * 4));
    float*    dinv   = (float*)(w + alloc((size_t)M * 4));
    int*      rowptr = (int*)(w + alloc((size_t)(M + 1) * 4));
    int*      csr    = (int*)(w + alloc((size_t)(E + 64) * 4));
    int*      bsum   = (int*)(w + alloc(256 * 4));
    int*      boff   = (int*)(w + alloc(256 * 4));

    hipMemsetAsync(cnt, 0, (size_t)((char*)cursor - (char*)cnt) + (size_t)M * 4, stream);

    // fused prep: count + pack_b
    const int nCount = (E + 255) / 256;
    WSegs segs;
    segs.s[0] = {Wp, WpPh, WpPl, 128, 192};
    segs.s[1] = {convW + 0 * 192 * 192, cWPh + 0 * 192 * 192, cWPl + 0 * 192 * 192, 192, 192};
    segs.s[2] = {convW + 1 * 192 * 192, cWPh + 1 * 192 * 192, cWPl + 1 * 192 * 192, 192, 192};
    segs.s[3] = {convW + 2 * 192 * 192, cWPh + 2 * 192 * 192, cWPl + 2 * 192 * 192, 192, 192};
    segs.s[4] = {convW + 3 * 192 * 192, cWPh + 3 * 192 * 192, cWPl + 3 * 192 * 192, 192, 192};
    segs.s[5] = {Wp1, Wp1Ph, Wp1Pl, 192, 192};
    segs.s[6] = {Wp2, Wp2Ph, Wp2Pl, 192, 96};
    segs.s[7] = {Wr1, Wr1Ph, nullptr, 192, 96};
    prep_kernel<<<nCount + 8 * 144, 256, 0, stream>>>(dstI, E, cnt, segs, nCount);

    int nb = (M + 255) / 256;
    scan1_kernel<<<nb, 256, 0, stream>>>(cnt, M, rowptr, bsum, dinv);
    scan2_kernel<<<1, 256, 0, stream>>>(bsum, nb, boff);
    scan3_kernel<<<(M + 256) / 256, 256, 0, stream>>>(rowptr, M, E, boff);
    fill_kernel<<<(E + 255) / 256, 256, 0, stream>>>(srcI, dstI, E, rowptr, cursor, csr);

    // HEAD: x -> h1 (planes) -> msc0
    head_kernel<<<RBp, 256, 0, stream>>>(
        x, WpPh, WpPl, bp, cWPh, cWPl, dinv, hpkH, hpkL, mscq, mscs, M);
    // 4 GCN layers: standalone wave-per-node aggregate; conv GEMM between
    for (int i = 0; i < 4; i++) {
        aggregate_kernel<<<(M + 3) / 4, 256, 0, stream>>>(
            mscq, mscs, csr, rowptr, dinv, convB + (size_t)i * 192, hpkH, hpkL, M);
        if (i < 3)
            conv_gemm_kernel<<<RBp, 256, 0, stream>>>(
                hpkH, hpkL, cWPh + (size_t)(i + 1) * 36864, cWPl + (size_t)(i + 1) * 36864,
                dinv, mscq, mscs, M);
    }
    // TAIL: p1+r (one h read) + p2 + in-register finalize
    tail_kernel<<<RBp, 256, 0, stream>>>(
        hpkH, hpkL, Wp1Ph, Wp1Pl, bp1, Wp2Ph, Wp2Pl, Wr1Ph, bp2, br1,
        Wp3, bp3, Wr2, br2, out, M);
}